// Round 11
// baseline (227.064 us; speedup 1.0000x reference)
//
#include <hip/hip_runtime.h>
#include <hip/hip_bf16.h>
#include <math.h>

typedef __attribute__((ext_vector_type(8))) short short8;
typedef __attribute__((ext_vector_type(4))) float floatx4;

static __device__ __forceinline__ unsigned short f2bf(float f) {
    union { float f; unsigned int u; } a; a.f = f;
    unsigned int u = a.u;
    return (unsigned short)((u + 0x7FFFu + ((u >> 16) & 1u)) >> 16);
}

// ---------------- fp32 -> bf16 convert, 8 elems/thread ----------------
static __device__ __forceinline__ void cvt8(const float* __restrict__ src,
                                            unsigned short* __restrict__ dst, int i) {
    float4 v0 = *(const float4*)(src + i);
    float4 v1 = *(const float4*)(src + i + 4);
    ushort4 o0, o1;
    o0.x = f2bf(v0.x); o0.y = f2bf(v0.y); o0.z = f2bf(v0.z); o0.w = f2bf(v0.w);
    o1.x = f2bf(v1.x); o1.y = f2bf(v1.y); o1.z = f2bf(v1.z); o1.w = f2bf(v1.w);
    *(ushort4*)(dst + i) = o0;
    *(ushort4*)(dst + i + 4) = o1;
}

// One launch: x (2048) + Wq/Wk/Wv (512 each) + l zero (1) + out zero (4096).
struct CV { const float* x; unsigned short* xb;
            const float* W[3]; unsigned short* Wb[3];
            float* l; float* out; };
__global__ __launch_bounds__(256)
void cvt_all(CV a) {
    int b = blockIdx.x, t = threadIdx.x;
    if (b < 2048) {
        cvt8(a.x, a.xb, (b * 256 + t) * 8);
    } else if (b < 3584) {
        int z  = (b - 2048) >> 9;
        int bb = (b - 2048) & 511;
        cvt8(a.W[z], a.Wb[z], (bb * 256 + t) * 8);
    } else if (b == 3584) {
        float4 zz = {0.f, 0.f, 0.f, 0.f};
        #pragma unroll
        for (int c = 0; c < 4; c++)
            *(float4*)(a.l + t * 16 + c * 4) = zz;
    } else {
        // zero out[] so osplit can atomicAdd into it (ws/out are poisoned)
        float4 zz = {0.f, 0.f, 0.f, 0.f};
        *(float4*)(a.out + ((b - 3585) * 256 + t) * 4) = zz;
    }
}

// ---------------- shared GEMM core: C += A B^T over k in [k_begin,k_end) ---
// LDS XOR-swizzle (conflict-free, verified r2/r5): slot (row, chunk c) holds
// global 16B-chunk c^(row & (BK/8-1)). global_load_lds width-16 staging.
template<int BM, int BN, int BK, int TI, int TJ, int WCOLS>
__device__ __forceinline__ void gemm_core(const unsigned short* __restrict__ A,
                                          const unsigned short* __restrict__ B,
                                          int lda, int k_begin, int k_end,
                                          unsigned short* sA, unsigned short* sB,
                                          floatx4 (&acc)[TI][TJ],
                                          int bm, int bn)
{
    constexpr int CPR = BK / 8;
    constexpr int RPR = 2048 / BK;
    const int t    = threadIdx.x;
    const int wave = t >> 6;
    const int lane = t & 63;
    const int wm = (wave / WCOLS) * (TI * 16);
    const int wn = (wave % WCOLS) * (TJ * 16);

    const int srow   = t / CPR;
    const int schunk = t % CPR;
    const int gchunk = schunk ^ (srow & (CPR - 1));
    const int lm  = lane & 15;
    const int swz = lm & (CPR - 1);

    for (int k0 = k_begin; k0 < k_end; k0 += BK) {
        __syncthreads();
        #pragma unroll
        for (int r = 0; r < (BM * BK) / 2048; r++) {
            const unsigned short* gA =
                A + (size_t)(bm + srow + r * RPR) * lda + k0 + gchunk * 8;
            __builtin_amdgcn_global_load_lds(
                (const __attribute__((address_space(1))) void*)gA,
                (__attribute__((address_space(3))) void*)((char*)sA + wave * 1024 + r * 4096),
                16, 0, 0);
        }
        #pragma unroll
        for (int r = 0; r < (BN * BK) / 2048; r++) {
            const unsigned short* gB =
                B + (size_t)(bn + srow + r * RPR) * lda + k0 + gchunk * 8;
            __builtin_amdgcn_global_load_lds(
                (const __attribute__((address_space(1))) void*)gB,
                (__attribute__((address_space(3))) void*)((char*)sB + wave * 1024 + r * 4096),
                16, 0, 0);
        }
        __syncthreads();

        #pragma unroll
        for (int kk = 0; kk < BK; kk += 32) {
            const int c  = (kk >> 3) + (lane >> 4);
            const int ce = ((c ^ swz) << 3);
            short8 a_frag[TI], b_frag[TJ];
            #pragma unroll
            for (int i = 0; i < TI; i++)
                a_frag[i] = *(const short8*)&sA[(wm + i * 16 + lm) * BK + ce];
            #pragma unroll
            for (int j = 0; j < TJ; j++)
                b_frag[j] = *(const short8*)&sB[(wn + j * 16 + lm) * BK + ce];
            #pragma unroll
            for (int i = 0; i < TI; i++)
                #pragma unroll
                for (int j = 0; j < TJ; j++)
                    acc[i][j] = __builtin_amdgcn_mfma_f32_16x16x32_bf16(
                        a_frag[i], b_frag[j], acc[i][j], 0, 0, 0);
        }
    }
}

// C/D layout (m89-verified): col = lane&15, row = (lane>>4)*4 + reg.

// ---- fused 3-way projection: {Wq->q(*1/32), Wk->k, Wv->vT} ----------------
// r10-verified: 128x128, BK=128, 64x64 wave tile, flat grid 768, 2-D XCD
// partition (each XCD: 8 row-tiles x 4 col-tiles x 3z = 5 MB L2-resident).
struct P3 { const unsigned short* W[3]; unsigned short* O[3]; };
__global__ __launch_bounds__(256)
void proj3(const unsigned short* __restrict__ xb, P3 a) {
    __shared__ unsigned short sA[128 * 128];
    __shared__ unsigned short sB[128 * 128];

    const int lid = blockIdx.x;                      // 0..767
    const int xcd = lid & 7;
    const int rem = lid >> 3;                        // 0..95
    const int row = (rem & 7) * 4 + (xcd >> 1);      // 0..31
    const int col = ((rem >> 3) & 3) * 2 + (xcd & 1);// 0..7
    const int z   = rem >> 5;                        // 0..2

    const unsigned short* B = a.W[z];
    unsigned short* O = a.O[z];
    const bool trans = (z == 2);
    const float scale = (z == 0) ? 0.03125f : 1.0f;

    floatx4 acc[4][4];
    #pragma unroll
    for (int i = 0; i < 4; i++)
        #pragma unroll
        for (int j = 0; j < 4; j++) { floatx4 zz = {0.f,0.f,0.f,0.f}; acc[i][j] = zz; }

    const int bm = row * 128, bn = col * 128;
    gemm_core<128, 128, 128, 4, 4, 2>(xb, B, 1024, 0, 1024, sA, sB, acc, bm, bn);

    const int lane = threadIdx.x & 63, wave = threadIdx.x >> 6;
    const int wm = (wave >> 1) * 64, wn = (wave & 1) * 64;
    const int lm = lane & 15, rq = (lane >> 4) * 4;
    #pragma unroll
    for (int i = 0; i < 4; i++)
        #pragma unroll
        for (int j = 0; j < 4; j++) {
            int tm = bm + wm + i * 16 + rq;
            int tn = bn + wn + j * 16 + lm;
            if (trans) {
                ushort4 h4;
                h4.x = f2bf(acc[i][j][0]);
                h4.y = f2bf(acc[i][j][1]);
                h4.z = f2bf(acc[i][j][2]);
                h4.w = f2bf(acc[i][j][3]);
                *(ushort4*)&O[(size_t)tn * 4096 + tm] = h4;
            } else {
                #pragma unroll
                for (int r = 0; r < 4; r++)
                    O[(size_t)(tm + r) * 1024 + tn] = f2bf(acc[i][j][r] * scale);
            }
        }
}

// ---- PS-GEMM: P = exp(q k^T) bf16 (scale pre-folded into q), row sums -> l -
// BK=64: LDS 32 KB -> 4 blocks/CU (2x TLP vs BK=128) to ride out memory
// latency (r10 showed ps latency-exposed at 2 blocks/CU). XCD-tiled grid
// (verified r6): each XCD covers a 16x8 region of the 32x32 tile grid.
__global__ __launch_bounds__(256)
void gemm_ps(const unsigned short* __restrict__ q, const unsigned short* __restrict__ k,
             unsigned short* __restrict__ Pm, float* __restrict__ l) {
    __shared__ unsigned short sA[128 * 64];
    __shared__ unsigned short sB[128 * 64];

    const int lid = blockIdx.x;
    const int xcd = lid & 7;
    const int i8  = lid >> 3;
    const int by  = (xcd & 1) * 16 + (i8 & 15);
    const int bx  = (xcd >> 1) * 8 + (i8 >> 4);

    floatx4 acc[4][4];
    #pragma unroll
    for (int i = 0; i < 4; i++)
        #pragma unroll
        for (int j = 0; j < 4; j++) { floatx4 zz = {0.f,0.f,0.f,0.f}; acc[i][j] = zz; }

    const int bm = by * 128, bn = bx * 128;
    gemm_core<128, 128, 64, 4, 4, 2>(q, k, 1024, 0, 1024, sA, sB, acc, bm, bn);

    const int lane = threadIdx.x & 63, wave = threadIdx.x >> 6;
    const int wm = (wave >> 1) * 64, wn = (wave & 1) * 64;
    const int lm = lane & 15, rq = (lane >> 4) * 4;
    #pragma unroll
    for (int i = 0; i < 4; i++) {
        #pragma unroll
        for (int r = 0; r < 4; r++) {
            int row = bm + wm + i * 16 + rq + r;
            float rs = 0.f;
            #pragma unroll
            for (int j = 0; j < 4; j++) {
                float e = __expf(acc[i][j][r]);
                rs += e;
                int tn = bn + wn + j * 16 + lm;
                Pm[(size_t)row * 4096 + tn] = f2bf(e);
            }
            rs += __shfl_xor(rs, 1);
            rs += __shfl_xor(rs, 2);
            rs += __shfl_xor(rs, 4);
            rs += __shfl_xor(rs, 8);
            if (lm == 0) atomicAdd(l + row, rs);  // device-scope, XCD-safe
        }
    }
}

// ---- O-GEMM split-K=2, fused epilogue: atomicAdd(out, acc/l[row]) ----------
// out = h0/l + h1/l; exactly 2 addends per address -> fp32 atomicAdd is
// order-independent (commutative) = deterministic. out pre-zeroed in cvt_all.
// Removes reduce_scale kernel + the Opart round-trip entirely.
// (r8-verified geometry: 128x128, BK=128, 64x64 wave tile, XCD strip grid.)
__global__ __launch_bounds__(256)
void gemm_osplit(const unsigned short* __restrict__ Pm, const unsigned short* __restrict__ vT,
                 const float* __restrict__ l, float* __restrict__ out) {
    __shared__ unsigned short sA[128 * 128];
    __shared__ unsigned short sB[128 * 128];

    const int lid = blockIdx.x;          // 0..511
    const int xcd = lid & 7;
    const int w   = lid >> 6;            // 0..7 window
    const int g   = (lid >> 3) & 7;      // column tile 0..7
    const int s   = w * 8 + xcd;         // strip 0..63
    const int z   = s >> 5;              // K half
    const int row = s & 31;              // row tile 0..31

    floatx4 acc[4][4];
    #pragma unroll
    for (int i = 0; i < 4; i++)
        #pragma unroll
        for (int j = 0; j < 4; j++) { floatx4 zz = {0.f,0.f,0.f,0.f}; acc[i][j] = zz; }

    const int bm = row * 128, bn = g * 128;
    gemm_core<128, 128, 128, 4, 4, 2>(Pm, vT, 4096, z * 2048, (z + 1) * 2048,
                                      sA, sB, acc, bm, bn);

    const int lane = threadIdx.x & 63, wave = threadIdx.x >> 6;
    const int wm = (wave >> 1) * 64, wn = (wave & 1) * 64;
    const int lm = lane & 15, rq = (lane >> 4) * 4;
    #pragma unroll
    for (int i = 0; i < 4; i++) {
        int tm = bm + wm + i * 16 + rq;
        float inv[4];
        #pragma unroll
        for (int r = 0; r < 4; r++) inv[r] = 1.0f / l[tm + r];
        #pragma unroll
        for (int j = 0; j < 4; j++) {
            int tn = bn + wn + j * 16 + lm;
            #pragma unroll
            for (int r = 0; r < 4; r++)
                atomicAdd(&out[(size_t)(tm + r) * 1024 + tn], acc[i][j][r] * inv[r]);
        }
    }
}

// ---------------- driver -----------------------------------------------
extern "C" void kernel_launch(void* const* d_in, const int* in_sizes, int n_in,
                              void* d_out, int out_size, void* d_ws, size_t ws_size,
                              hipStream_t stream) {
    const float* x  = (const float*)d_in[0];
    const float* Wq = (const float*)d_in[1];
    const float* Wk = (const float*)d_in[2];
    const float* Wv = (const float*)d_in[3];
    float* out = (float*)d_out;

    const int SEQ = 4096, D = 1024;
    char* ws = (char*)d_ws;
    const size_t MB = 1u << 20;
    unsigned short* vTb = (unsigned short*)(ws);             //  0..8   bf16 [D x SEQ]
    unsigned short* xb  = (unsigned short*)(ws + 8 * MB);    //  8..16
    unsigned short* Wqb = (unsigned short*)(ws + 16 * MB);   // 16..18
    unsigned short* Wkb = (unsigned short*)(ws + 18 * MB);   // 18..20
    unsigned short* Wvb = (unsigned short*)(ws + 20 * MB);   // 20..22
    unsigned short* qb  = (unsigned short*)(ws + 22 * MB);   // 22..30
    unsigned short* kb  = (unsigned short*)(ws + 30 * MB);   // 30..38
    unsigned short* P   = (unsigned short*)(ws + 38 * MB);   // 38..70  bf16 [SEQ x SEQ]
    float*          l   = (float*)(ws + 70 * MB);            // 70..70.016 row sums

    dim3 blk(256);
    // converts + l zero + out zero (4096 tail blocks)
    CV cv = {x, xb, {Wq, Wk, Wv}, {Wqb, Wkb, Wvb}, l, out};
    cvt_all<<<dim3(7681), blk, 0, stream>>>(cv);

    // q(*1/32)/k/vT: 128x128 tile, BK=128, flat grid 768, 2-D XCD partition.
    P3 p3 = {{Wqb, Wkb, Wvb}, {qb, kb, vTb}};
    proj3<<<dim3(768), blk, 0, stream>>>(xb, p3);

    // P = exp(q k^T) bf16 + row sums l (128x128, BK=64, XCD-tiled grid)
    gemm_ps<<<dim3(1024), blk, 0, stream>>>(qb, kb, P, l);

    // out += (P @ vT^T)/l per K-half (128x128, BK=128, split-K=2, XCD grid)
    gemm_osplit<<<dim3(512), blk, 0, stream>>>(P, vTb, l, out);
}

// Round 12
// 199.736 us; speedup vs baseline: 1.1368x; 1.1368x over previous
//
#include <hip/hip_runtime.h>
#include <hip/hip_bf16.h>
#include <math.h>

typedef __attribute__((ext_vector_type(8))) short short8;
typedef __attribute__((ext_vector_type(4))) float floatx4;

static __device__ __forceinline__ unsigned short f2bf(float f) {
    union { float f; unsigned int u; } a; a.f = f;
    unsigned int u = a.u;
    return (unsigned short)((u + 0x7FFFu + ((u >> 16) & 1u)) >> 16);
}
static __device__ __forceinline__ float bf2f(unsigned short h) {
    union { unsigned int u; float f; } a; a.u = ((unsigned int)h) << 16;
    return a.f;
}

// ---------------- fp32 -> bf16 convert, 8 elems/thread ----------------
static __device__ __forceinline__ void cvt8(const float* __restrict__ src,
                                            unsigned short* __restrict__ dst, int i) {
    float4 v0 = *(const float4*)(src + i);
    float4 v1 = *(const float4*)(src + i + 4);
    ushort4 o0, o1;
    o0.x = f2bf(v0.x); o0.y = f2bf(v0.y); o0.z = f2bf(v0.z); o0.w = f2bf(v0.w);
    o1.x = f2bf(v1.x); o1.y = f2bf(v1.y); o1.z = f2bf(v1.z); o1.w = f2bf(v1.w);
    *(ushort4*)(dst + i) = o0;
    *(ushort4*)(dst + i + 4) = o1;
}

// One launch: x (2048 blks) + Wq/Wk/Wv (512 blks each) + l zero (1 blk).
struct CV { const float* x; unsigned short* xb;
            const float* W[3]; unsigned short* Wb[3]; float* l; };
__global__ __launch_bounds__(256)
void cvt_all(CV a) {
    int b = blockIdx.x, t = threadIdx.x;
    if (b < 2048) {
        cvt8(a.x, a.xb, (b * 256 + t) * 8);
    } else if (b < 3584) {
        int z  = (b - 2048) >> 9;
        int bb = (b - 2048) & 511;
        cvt8(a.W[z], a.Wb[z], (bb * 256 + t) * 8);
    } else {
        float4 zz = {0.f, 0.f, 0.f, 0.f};
        #pragma unroll
        for (int c = 0; c < 4; c++)
            *(float4*)(a.l + t * 16 + c * 4) = zz;
    }
}

// ---------------- shared GEMM core: C += A B^T over k in [k_begin,k_end) ---
// LDS XOR-swizzle (conflict-free, verified r2/r5): slot (row, chunk c) holds
// global 16B-chunk c^(row & (BK/8-1)). global_load_lds width-16 staging.
template<int BM, int BN, int BK, int TI, int TJ, int WCOLS>
__device__ __forceinline__ void gemm_core(const unsigned short* __restrict__ A,
                                          const unsigned short* __restrict__ B,
                                          int lda, int k_begin, int k_end,
                                          unsigned short* sA, unsigned short* sB,
                                          floatx4 (&acc)[TI][TJ],
                                          int bm, int bn)
{
    constexpr int CPR = BK / 8;
    constexpr int RPR = 2048 / BK;
    const int t    = threadIdx.x;
    const int wave = t >> 6;
    const int lane = t & 63;
    const int wm = (wave / WCOLS) * (TI * 16);
    const int wn = (wave % WCOLS) * (TJ * 16);

    const int srow   = t / CPR;
    const int schunk = t % CPR;
    const int gchunk = schunk ^ (srow & (CPR - 1));
    const int lm  = lane & 15;
    const int swz = lm & (CPR - 1);

    for (int k0 = k_begin; k0 < k_end; k0 += BK) {
        __syncthreads();
        #pragma unroll
        for (int r = 0; r < (BM * BK) / 2048; r++) {
            const unsigned short* gA =
                A + (size_t)(bm + srow + r * RPR) * lda + k0 + gchunk * 8;
            __builtin_amdgcn_global_load_lds(
                (const __attribute__((address_space(1))) void*)gA,
                (__attribute__((address_space(3))) void*)((char*)sA + wave * 1024 + r * 4096),
                16, 0, 0);
        }
        #pragma unroll
        for (int r = 0; r < (BN * BK) / 2048; r++) {
            const unsigned short* gB =
                B + (size_t)(bn + srow + r * RPR) * lda + k0 + gchunk * 8;
            __builtin_amdgcn_global_load_lds(
                (const __attribute__((address_space(1))) void*)gB,
                (__attribute__((address_space(3))) void*)((char*)sB + wave * 1024 + r * 4096),
                16, 0, 0);
        }
        __syncthreads();

        #pragma unroll
        for (int kk = 0; kk < BK; kk += 32) {
            const int c  = (kk >> 3) + (lane >> 4);
            const int ce = ((c ^ swz) << 3);
            short8 a_frag[TI], b_frag[TJ];
            #pragma unroll
            for (int i = 0; i < TI; i++)
                a_frag[i] = *(const short8*)&sA[(wm + i * 16 + lm) * BK + ce];
            #pragma unroll
            for (int j = 0; j < TJ; j++)
                b_frag[j] = *(const short8*)&sB[(wn + j * 16 + lm) * BK + ce];
            #pragma unroll
            for (int i = 0; i < TI; i++)
                #pragma unroll
                for (int j = 0; j < TJ; j++)
                    acc[i][j] = __builtin_amdgcn_mfma_f32_16x16x32_bf16(
                        a_frag[i], b_frag[j], acc[i][j], 0, 0, 0);
        }
    }
}

// C/D layout (m89-verified): col = lane&15, row = (lane>>4)*4 + reg.

// ---- LDS-staged coalesced tile store (128x128 bf16) ------------------------
// Epilogue stores were 2B/8B scattered (32B segments) -> L2 write-allocate
// fetched each output line from HBM first (ps FETCH 43 MB vs 16 MB inputs).
// Fix: deposit the tile in LDS (stride 136: 16B-aligned rows, ~2-way banks),
// then stream out full 256B-per-row dwordx4 stores (full lines, no allocate).
__device__ __forceinline__ void tile_store(unsigned short* sm,  // >= 128*136
                                           unsigned short (&vals)[4][4][4], int trans,
                                           unsigned short* __restrict__ C, int ldc,
                                           int rbase, int cbase)
{
    const int t = threadIdx.x, wave = t >> 6, lane = t & 63;
    const int wm = (wave >> 1) * 64, wn = (wave & 1) * 64;
    const int lm = lane & 15, rq = (lane >> 4) * 4;
    __syncthreads();   // all waves done reading sA/sB (aliased with sm)
    #pragma unroll
    for (int i = 0; i < 4; i++)
        #pragma unroll
        for (int j = 0; j < 4; j++)
            #pragma unroll
            for (int r = 0; r < 4; r++) {
                int rr = trans ? (wn + j * 16 + lm) : (wm + i * 16 + rq + r);
                int cc = trans ? (wm + i * 16 + rq + r) : (wn + j * 16 + lm);
                sm[rr * 136 + cc] = vals[i][j][r];
            }
    __syncthreads();
    const int row = t >> 4, c16 = t & 15;
    #pragma unroll
    for (int p = 0; p < 8; p++) {
        int rr = p * 16 + row;
        short8 v = *(const short8*)&sm[rr * 136 + c16 * 8];
        *(short8*)&C[(size_t)(rbase + rr) * ldc + cbase + c16 * 8] = v;
    }
}

// ---- fused 3-way projection: {Wq->q(*1/32), Wk->k, Wv->vT} ----------------
// r10-verified geometry: 128x128, BK=128, 64x64 wave tile, flat grid 768,
// 2-D XCD partition (each XCD: 5 MB L2-resident working set).
struct P3 { const unsigned short* W[3]; unsigned short* O[3]; };
__global__ __launch_bounds__(256)
void proj3(const unsigned short* __restrict__ xb, P3 a) {
    __shared__ unsigned short sm[2 * 128 * 128];   // staging + epilogue reuse
    unsigned short* sA = sm;
    unsigned short* sB = sm + 128 * 128;

    const int lid = blockIdx.x;                      // 0..767
    const int xcd = lid & 7;
    const int rem = lid >> 3;                        // 0..95
    const int row = (rem & 7) * 4 + (xcd >> 1);      // 0..31
    const int col = ((rem >> 3) & 3) * 2 + (xcd & 1);// 0..7
    const int z   = rem >> 5;                        // 0..2

    const unsigned short* B = a.W[z];
    unsigned short* O = a.O[z];
    const int trans = (z == 2);
    const float scale = (z == 0) ? 0.03125f : 1.0f;

    floatx4 acc[4][4];
    #pragma unroll
    for (int i = 0; i < 4; i++)
        #pragma unroll
        for (int j = 0; j < 4; j++) { floatx4 zz = {0.f,0.f,0.f,0.f}; acc[i][j] = zz; }

    const int bm = row * 128, bn = col * 128;
    gemm_core<128, 128, 128, 4, 4, 2>(xb, B, 1024, 0, 1024, sA, sB, acc, bm, bn);

    unsigned short vals[4][4][4];
    #pragma unroll
    for (int i = 0; i < 4; i++)
        #pragma unroll
        for (int j = 0; j < 4; j++)
            #pragma unroll
            for (int r = 0; r < 4; r++)
                vals[i][j][r] = f2bf(acc[i][j][r] * scale);

    tile_store(sm, vals, trans, O, trans ? 4096 : 1024,
               trans ? bn : bm, trans ? bm : bn);
}

// ---- PS-GEMM: P = exp(q k^T) bf16 (scale pre-folded into q), row sums -> l -
// BK=128 (r9 best: 49.6 us). XCD-tiled grid (verified r6).
__global__ __launch_bounds__(256)
void gemm_ps(const unsigned short* __restrict__ q, const unsigned short* __restrict__ k,
             unsigned short* __restrict__ Pm, float* __restrict__ l) {
    __shared__ unsigned short sm[2 * 128 * 128];
    unsigned short* sA = sm;
    unsigned short* sB = sm + 128 * 128;

    const int lid = blockIdx.x;
    const int xcd = lid & 7;
    const int i8  = lid >> 3;
    const int by  = (xcd & 1) * 16 + (i8 & 15);
    const int bx  = (xcd >> 1) * 8 + (i8 >> 4);

    floatx4 acc[4][4];
    #pragma unroll
    for (int i = 0; i < 4; i++)
        #pragma unroll
        for (int j = 0; j < 4; j++) { floatx4 zz = {0.f,0.f,0.f,0.f}; acc[i][j] = zz; }

    const int bm = by * 128, bn = bx * 128;
    gemm_core<128, 128, 128, 4, 4, 2>(q, k, 1024, 0, 1024, sA, sB, acc, bm, bn);

    const int lane = threadIdx.x & 63, wave = threadIdx.x >> 6;
    const int wm = (wave >> 1) * 64;
    const int lm = lane & 15, rq = (lane >> 4) * 4;
    unsigned short vals[4][4][4];
    #pragma unroll
    for (int i = 0; i < 4; i++) {
        #pragma unroll
        for (int r = 0; r < 4; r++) {
            int row = bm + wm + i * 16 + rq + r;
            float rs = 0.f;
            #pragma unroll
            for (int j = 0; j < 4; j++) {
                float e = __expf(acc[i][j][r]);
                rs += e;
                vals[i][j][r] = f2bf(e);
            }
            rs += __shfl_xor(rs, 1);
            rs += __shfl_xor(rs, 2);
            rs += __shfl_xor(rs, 4);
            rs += __shfl_xor(rs, 8);
            if (lm == 0) atomicAdd(l + row, rs);  // device-scope, XCD-safe
        }
    }
    tile_store(sm, vals, 0, Pm, 4096, bm, bn);
}

// ---- O-GEMM split-K=2: 128x128 tile, BK=128, bf16 partials -----------------
// (r8-verified geometry + XCD strip grid; r10-verified bf16 partials.)
__global__ __launch_bounds__(256)
void gemm_osplit(const unsigned short* __restrict__ Pm, const unsigned short* __restrict__ vT,
                 unsigned short* __restrict__ Opart) {
    __shared__ unsigned short sm[2 * 128 * 128];
    unsigned short* sA = sm;
    unsigned short* sB = sm + 128 * 128;

    const int lid = blockIdx.x;          // 0..511
    const int xcd = lid & 7;
    const int w   = lid >> 6;            // 0..7 window
    const int g   = (lid >> 3) & 7;      // column tile 0..7
    const int s   = w * 8 + xcd;         // strip 0..63
    const int z   = s >> 5;              // K half
    const int row = s & 31;              // row tile 0..31

    floatx4 acc[4][4];
    #pragma unroll
    for (int i = 0; i < 4; i++)
        #pragma unroll
        for (int j = 0; j < 4; j++) { floatx4 zz = {0.f,0.f,0.f,0.f}; acc[i][j] = zz; }

    const int bm = row * 128, bn = g * 128;
    gemm_core<128, 128, 128, 4, 4, 2>(Pm, vT, 4096, z * 2048, (z + 1) * 2048,
                                      sA, sB, acc, bm, bn);

    unsigned short vals[4][4][4];
    #pragma unroll
    for (int i = 0; i < 4; i++)
        #pragma unroll
        for (int j = 0; j < 4; j++)
            #pragma unroll
            for (int r = 0; r < 4; r++)
                vals[i][j][r] = f2bf(acc[i][j][r]);

    tile_store(sm, vals, 0, Opart + (size_t)z * (4096 * 1024), 1024, bm, bn);
}

// ---- reduce bf16 split-K halves + apply deferred 1/l row scale -------------
__global__ __launch_bounds__(256)
void reduce_scale(const unsigned short* __restrict__ Op, const float* __restrict__ l,
                  float* __restrict__ out) {
    int i = (blockIdx.x * 256 + threadIdx.x) * 4;
    ushort4 a = *(const ushort4*)(Op + i);
    ushort4 b = *(const ushort4*)(Op + 4096 * 1024 + i);
    float inv = 1.0f / l[i >> 10];
    float4 o;
    o.x = (bf2f(a.x) + bf2f(b.x)) * inv;
    o.y = (bf2f(a.y) + bf2f(b.y)) * inv;
    o.z = (bf2f(a.z) + bf2f(b.z)) * inv;
    o.w = (bf2f(a.w) + bf2f(b.w)) * inv;
    *(float4*)(out + i) = o;
}

// ---------------- driver -----------------------------------------------
extern "C" void kernel_launch(void* const* d_in, const int* in_sizes, int n_in,
                              void* d_out, int out_size, void* d_ws, size_t ws_size,
                              hipStream_t stream) {
    const float* x  = (const float*)d_in[0];
    const float* Wq = (const float*)d_in[1];
    const float* Wk = (const float*)d_in[2];
    const float* Wv = (const float*)d_in[3];
    float* out = (float*)d_out;

    const int SEQ = 4096, D = 1024;
    char* ws = (char*)d_ws;
    const size_t MB = 1u << 20;
    unsigned short* vTb = (unsigned short*)(ws);             //  0..8   bf16 [D x SEQ]
    unsigned short* xb  = (unsigned short*)(ws + 8 * MB);    //  8..16
    unsigned short* Wqb = (unsigned short*)(ws + 16 * MB);   // 16..18
    unsigned short* Wkb = (unsigned short*)(ws + 18 * MB);   // 18..20
    unsigned short* Wvb = (unsigned short*)(ws + 20 * MB);   // 20..22
    unsigned short* qb  = (unsigned short*)(ws + 22 * MB);   // 22..30
    unsigned short* kb  = (unsigned short*)(ws + 30 * MB);   // 30..38
    unsigned short* P   = (unsigned short*)(ws + 38 * MB);   // 38..70  bf16 [SEQ x SEQ]
    float*          l   = (float*)(ws + 70 * MB);            // 70..70.016 row sums
    unsigned short* Opart = (unsigned short*)(ws + 72 * MB); // 72..88  bf16 2x[SEQ x D]

    dim3 blk(256);
    CV cv = {x, xb, {Wq, Wk, Wv}, {Wqb, Wkb, Wvb}, l};
    cvt_all<<<dim3(3585), blk, 0, stream>>>(cv);

    // q(*1/32)/k/vT: 128x128 tile, BK=128, flat grid 768, 2-D XCD partition.
    P3 p3 = {{Wqb, Wkb, Wvb}, {qb, kb, vTb}};
    proj3<<<dim3(768), blk, 0, stream>>>(xb, p3);

    // P = exp(q k^T) bf16 + row sums l (128x128, BK=128, XCD-tiled grid)
    gemm_ps<<<dim3(1024), blk, 0, stream>>>(qb, kb, P, l);

    // O partials bf16 (128x128, BK=128, split-K=2, XCD strip grid)
    gemm_osplit<<<dim3(512), blk, 0, stream>>>(P, vTb, Opart);

    // out = (half0 + half1) / l[row]
    reduce_scale<<<(SEQ * D) / 1024, blk, 0, stream>>>(Opart, l, out);
}